// Round 2
// baseline (1310.249 us; speedup 1.0000x reference)
//
#include <hip/hip_runtime.h>
#include <float.h>

// Problem constants (B=32 queries, D=128, K=16).
#define BQ 32
#define DIM 128
#define TOPK 16
#define T1 256          // phase-1 threads (4 waves)
#define T2 256          // phase-2 threads
#define GBLK 992        // max phase-1 blocks (runtime-capped by ws_size)
#define RPL 4           // rows per lane in the dot loop
#define UROWS (64*RPL)  // rows per wave-unit = 256
#define NCAND (GBLK*TOPK)  // 15872 = 62*256 exactly

// ---------------- phase 0: q = query @ Wq^T + bq -> qpack[dq][b] float4 + norms ----------
__global__ void ph0_qproj(const float* __restrict__ query, const float* __restrict__ Wq,
                          const float* __restrict__ bq,
                          float* __restrict__ qpackf, float* __restrict__ qn2,
                          float* __restrict__ sinvq)
{
    const int b = blockIdx.x;     // query row
    const int d = threadIdx.x;    // output dim
    float s = bq[d];
    #pragma unroll 8
    for (int kk = 0; kk < DIM; ++kk)
        s = fmaf(query[b * DIM + kk], Wq[d * DIM + kk], s);
    // qpack layout: element (dq, b, j) at (dq*32 + b)*4 + j, with d = dq*4 + j
    qpackf[(d >> 2) * (BQ * 4) + b * 4 + (d & 3)] = s;
    __shared__ float red[DIM];
    red[d] = s * s;
    __syncthreads();
    for (int off = DIM / 2; off >= 1; off >>= 1) {
        if (d < off) red[d] += red[d + off];
        __syncthreads();
    }
    if (d == 0) {
        qn2[b] = red[0];
        sinvq[b] = 1.0f / sqrtf(red[0]);
    }
}

// ---------------- phase 1: scores + per-block top-16/query + min-d2 ----------
__global__ __launch_bounds__(T1, 2) void ph1_scan(
    const float* __restrict__ mem, const float* __restrict__ imp,
    const int* __restrict__ tsp, const float* __restrict__ qpackg,
    const float* __restrict__ sinvq, const float* __restrict__ qn2,
    const int* __restrict__ ctp,
    float* __restrict__ cand_sc, int* __restrict__ cand_ix,
    float* __restrict__ minD_ws, int N, int wstride)
{
    // [0,4096): qpack staged (16 KB). [4096,13312): per-wave transpose bufs / merge arrays.
    __shared__ float smem[13312];   // 52 KB

    const int tid  = threadIdx.x;
    const int wave = tid >> 6;
    const int lane = tid & 63;
    const int qsel = lane & 31;
    const int hsel = lane >> 5;
    const int g = blockIdx.x;

    // stage qpack global -> LDS (1024 float4)
    {
        const float4* src = (const float4*)qpackg;
        float4* dst = (float4*)smem;
        #pragma unroll
        for (int i = 0; i < 4; ++i) dst[tid + i * T1] = src[tid + i * T1];
    }
    __syncthreads();
    const float4* qlds = (const float4*)smem;
    float* tb = smem + 4096 + wave * (64 * 36);

    const float invct = 1.0f / ((float)(*ctp) + 1.0f);
    const float sq   = sinvq[qsel];
    const float qn2s = qn2[qsel];

    float top_s[TOPK];
    int   top_i[TOPK];
    #pragma unroll
    for (int j = 0; j < TOPK; ++j) { top_s[j] = -FLT_MAX; top_i[j] = 0; }
    float mind = FLT_MAX;

    const int units = (N + UROWS - 1) / UROWS;

    for (int u = g * 4 + wave; u < units; u += wstride) {
        const int rowbase = u * UROWS + lane;
        int rows[RPL]; bool vld[RPL];
        #pragma unroll
        for (int s = 0; s < RPL; ++s) { rows[s] = rowbase + s * 64; vld[s] = rows[s] < N; }
        const float4* mr0 = (const float4*)(mem + (size_t)(vld[0] ? rows[0] : N - 1) * DIM);
        const float4* mr1 = (const float4*)(mem + (size_t)(vld[1] ? rows[1] : N - 1) * DIM);
        const float4* mr2 = (const float4*)(mem + (size_t)(vld[2] ? rows[2] : N - 1) * DIM);
        const float4* mr3 = (const float4*)(mem + (size_t)(vld[3] ? rows[3] : N - 1) * DIM);

        float acc[RPL][BQ];
        #pragma unroll
        for (int s = 0; s < RPL; ++s)
            #pragma unroll
            for (int b = 0; b < BQ; ++b) acc[s][b] = 0.0f;
        float m2[RPL];
        #pragma unroll
        for (int s = 0; s < RPL; ++s) m2[s] = 0.0f;

        float4 n0 = mr0[0], n1 = mr1[0], n2 = mr2[0], n3 = mr3[0];

        #pragma unroll 1
        for (int dq = 0; dq < DIM / 4; ++dq) {
            const float4 u0 = n0, u1 = n1, u2 = n2, u3 = n3;
            const int nq = (dq < DIM / 4 - 1) ? dq + 1 : dq;   // prefetch next quad
            n0 = mr0[nq]; n1 = mr1[nq]; n2 = mr2[nq]; n3 = mr3[nq];

            m2[0] = fmaf(u0.x, u0.x, fmaf(u0.y, u0.y, fmaf(u0.z, u0.z, fmaf(u0.w, u0.w, m2[0]))));
            m2[1] = fmaf(u1.x, u1.x, fmaf(u1.y, u1.y, fmaf(u1.z, u1.z, fmaf(u1.w, u1.w, m2[1]))));
            m2[2] = fmaf(u2.x, u2.x, fmaf(u2.y, u2.y, fmaf(u2.z, u2.z, fmaf(u2.w, u2.w, m2[2]))));
            m2[3] = fmaf(u3.x, u3.x, fmaf(u3.y, u3.y, fmaf(u3.z, u3.z, fmaf(u3.w, u3.w, m2[3]))));

            #pragma unroll
            for (int b = 0; b < BQ; ++b) {
                const float4 qv = qlds[dq * BQ + b];   // wave-uniform address -> LDS broadcast
                acc[0][b] = fmaf(u0.x, qv.x, acc[0][b]);
                acc[0][b] = fmaf(u0.y, qv.y, acc[0][b]);
                acc[0][b] = fmaf(u0.z, qv.z, acc[0][b]);
                acc[0][b] = fmaf(u0.w, qv.w, acc[0][b]);
                acc[1][b] = fmaf(u1.x, qv.x, acc[1][b]);
                acc[1][b] = fmaf(u1.y, qv.y, acc[1][b]);
                acc[1][b] = fmaf(u1.z, qv.z, acc[1][b]);
                acc[1][b] = fmaf(u1.w, qv.w, acc[1][b]);
                acc[2][b] = fmaf(u2.x, qv.x, acc[2][b]);
                acc[2][b] = fmaf(u2.y, qv.y, acc[2][b]);
                acc[2][b] = fmaf(u2.z, qv.z, acc[2][b]);
                acc[2][b] = fmaf(u2.w, qv.w, acc[2][b]);
                acc[3][b] = fmaf(u3.x, qv.x, acc[3][b]);
                acc[3][b] = fmaf(u3.y, qv.y, acc[3][b]);
                acc[3][b] = fmaf(u3.z, qv.z, acc[3][b]);
                acc[3][b] = fmaf(u3.w, qv.w, acc[3][b]);
            }
        }

        // scoring: 4 transpose passes of 64 rows each through the wave-private buffer
        #pragma unroll 1
        for (int s = 0; s < RPL; ++s) {
            float k1, k2v, m2v;
            if (vld[s]) {
                const float invm = rsqrtf(m2[s]);
                const float recn = ((float)tsp[rows[s]] + 1.0f) * invct;
                const float impf = fmaf(0.5f, imp[rows[s]], 0.5f);
                k1 = 0.7f * invm * impf;
                k2v = 0.3f * recn * impf;
                m2v = m2[s];
            } else {
                k1 = 0.0f; k2v = -FLT_MAX; m2v = 3.0e37f;
            }
            #pragma unroll
            for (int b = 0; b < BQ; ++b) tb[lane * 36 + b] = acc[s][b];
            tb[lane * 36 + 32] = k1;
            tb[lane * 36 + 33] = k2v;
            tb[lane * 36 + 34] = m2v;
            tb[lane * 36 + 35] = 0.0f;
            // same-wave DS ordering: compiler inserts lgkmcnt before dependent reads
            #pragma unroll 1
            for (int j = 0; j < 32; ++j) {
                const int rr = (hsel << 5) + j;
                const float a = tb[rr * 36 + qsel];
                const float4 kk = *(const float4*)&tb[rr * 36 + 32]; // k1,k2,m2,pad
                const float score = fmaf(a, kk.x * sq, kk.y);
                const float d2 = fmaf(-2.0f, a, qn2s + kk.z);
                mind = fminf(mind, d2);
                if (score > top_s[TOPK - 1]) {
                    float cs = score; int ci = u * UROWS + s * 64 + rr;
                    #pragma unroll
                    for (int p = 0; p < TOPK; ++p) {
                        const bool gt = cs > top_s[p];
                        const float tv = top_s[p]; const int tx = top_i[p];
                        top_s[p] = gt ? cs : tv;  top_i[p] = gt ? ci : tx;
                        cs = gt ? tv : cs;        ci = gt ? tx : ci;
                    }
                }
            }
        }
    }

    // ---- block merge: dump lists to LDS, per-query 128 -> 16 extraction ----
    __syncthreads();
    float* dsc = smem + 4096;             // 256*16 floats
    int*   dix = (int*)(dsc + T1 * TOPK); // 256*16 ints
    float* dmn = dsc + 2 * T1 * TOPK;     // 256 floats
    #pragma unroll
    for (int j = 0; j < TOPK; ++j) {
        dsc[tid * TOPK + j] = top_s[j];
        dix[tid * TOPK + j] = top_i[j];
    }
    dmn[tid] = mind;
    __syncthreads();

    for (int qq = 0; qq < 8; ++qq) {
        const int q = wave * 8 + qq;
        // 8 lists of 16 -> 128 candidates; 2 per lane
        float sc2[2]; int ix2[2];
        #pragma unroll
        for (int s = 0; s < 2; ++s) {
            const int c = lane * 2 + s;
            const int L = (c >> 4) * 32 + q;
            const int slot = c & 15;
            sc2[s] = dsc[L * TOPK + slot];
            ix2[s] = dix[L * TOPK + slot];
        }
        float lm = (sc2[0] >= sc2[1]) ? sc2[0] : sc2[1];
        int   ls = (sc2[0] >= sc2[1]) ? 0 : 1;
        for (int r = 0; r < TOPK; ++r) {
            float v = lm; int we = lane;
            #pragma unroll
            for (int off = 32; off >= 1; off >>= 1) {
                const float ov = __shfl_xor(v, off);
                const int   oe = __shfl_xor(we, off);
                if (ov > v || (ov == v && oe < we)) { v = ov; we = oe; }
            }
            if (lane == we) {
                cand_sc[(g * 32 + q) * TOPK + r] = lm;
                cand_ix[(g * 32 + q) * TOPK + r] = ix2[ls];
                sc2[ls] = -FLT_MAX;
                lm = (sc2[0] >= sc2[1]) ? sc2[0] : sc2[1];
                ls = (sc2[0] >= sc2[1]) ? 0 : 1;
            }
        }
    }

    if (tid < 32) {
        float m = FLT_MAX;
        #pragma unroll
        for (int l = 0; l < 8; ++l) m = fminf(m, dmn[l * 32 + tid]);
        minD_ws[g * 32 + tid] = m;
    }
}

// ---------------- phase 2: global top-16/query + novelty ----------
__global__ void ph2_final(const float* __restrict__ cand_sc, const int* __restrict__ cand_ix,
                          const float* __restrict__ minD_ws, float* __restrict__ out, int G)
{
    __shared__ float ssc[NCAND];          // 62 KB
    __shared__ float shv[4];
    __shared__ int   she[4];
    __shared__ float smin[T2];

    const int q = blockIdx.x;
    const int tid = threadIdx.x;
    const int wave = tid >> 6;
    const int lane = tid & 63;
    const int gcand = G * TOPK;

    for (int e = tid; e < NCAND; e += T2)
        ssc[e] = (e < gcand) ? cand_sc[(e >> 4) * (32 * TOPK) + q * TOPK + (e & 15)] : -FLT_MAX;
    __syncthreads();

    // local argmax over this thread's 62 slots (e = s*256 + tid)
    float lm = ssc[tid]; int le = tid;
    for (int s = 1; s < NCAND / T2; ++s) {
        const int e = s * T2 + tid;
        const float v = ssc[e];
        if (v > lm) { lm = v; le = e; }
    }

    for (int r = 0; r < TOPK; ++r) {
        float v = lm; int e = le;
        #pragma unroll
        for (int off = 32; off >= 1; off >>= 1) {
            const float ov = __shfl_xor(v, off);
            const int   oe = __shfl_xor(e, off);
            if (ov > v || (ov == v && oe < e)) { v = ov; e = oe; }
        }
        if (lane == 0) { shv[wave] = v; she[wave] = e; }
        __syncthreads();
        float bv = shv[0]; int be = she[0];
        #pragma unroll
        for (int w2 = 1; w2 < 4; ++w2) {
            const float wv = shv[w2]; const int we2 = she[w2];
            if (wv > bv || (wv == bv && we2 < be)) { bv = wv; be = we2; }
        }
        if (le == be) {   // unique winner thread
            out[q * TOPK + r] = bv;
            const int gix = cand_ix[(be >> 4) * (32 * TOPK) + q * TOPK + (be & 15)];
            out[BQ * TOPK + q * TOPK + r] = (float)gix;
            ssc[le] = -FLT_MAX;
            lm = ssc[tid]; le = tid;
            for (int s = 1; s < NCAND / T2; ++s) {
                const int e2 = s * T2 + tid;
                const float v2 = ssc[e2];
                if (v2 > lm) { lm = v2; le = e2; }
            }
        }
        __syncthreads();
    }

    // novelty
    float m = FLT_MAX;
    for (int g2 = tid; g2 < G; g2 += T2) m = fminf(m, minD_ws[g2 * 32 + q]);
    smin[tid] = m;
    __syncthreads();
    for (int off = T2 / 2; off >= 1; off >>= 1) {
        if (tid < off) smin[tid] = fminf(smin[tid], smin[tid + off]);
        __syncthreads();
    }
    if (tid == 0) {
        const float md = sqrtf(fmaxf(smin[0], 0.0f));
        out[2 * BQ * TOPK + q] = fminf(1.0f, md * 0.1f);
    }
}

extern "C" void kernel_launch(void* const* d_in, const int* in_sizes, int n_in,
                              void* d_out, int out_size, void* d_ws, size_t ws_size,
                              hipStream_t stream) {
    const float* query      = (const float*)d_in[0];
    const float* memory     = (const float*)d_in[1];
    const float* importance = (const float*)d_in[2];
    const int*   timestamps = (const int*)d_in[3];
    const float* Wq         = (const float*)d_in[4];
    const float* bq         = (const float*)d_in[5];
    const int*   ctp        = (const int*)d_in[6];
    const int N = in_sizes[2];

    // runtime-cap block count by workspace capacity (floats): 4352 + gb*(512*2 + 32)
    const size_t ws_floats = ws_size / 4;
    int gb = GBLK;
    if (ws_floats < (size_t)4352 + (size_t)GBLK * 1056) {
        gb = (int)((ws_floats - 4352) / 1056);
        if (gb < 1) gb = 1;
    }

    float* ws      = (float*)d_ws;
    float* qpack   = ws;                       // 4096
    float* qn2     = ws + 4096;                // 32
    float* sinvq   = ws + 4128;                // 32
    float* cand_sc = ws + 4352;                // gb*512
    int*   cand_ix = (int*)(ws + 4352 + (size_t)gb * 512);
    float* minD_ws = ws + 4352 + 2 * (size_t)gb * 512;  // gb*32

    ph0_qproj<<<BQ, DIM, 0, stream>>>(query, Wq, bq, qpack, qn2, sinvq);
    ph1_scan<<<gb, T1, 0, stream>>>(memory, importance, timestamps, qpack, sinvq, qn2,
                                    ctp, cand_sc, cand_ix, minD_ws, N, gb * 4);
    ph2_final<<<BQ, T2, 0, stream>>>(cand_sc, cand_ix, minD_ws, (float*)d_out, gb);
}